// Round 11
// baseline (1519.464 us; speedup 1.0000x reference)
//
#include <hip/hip_runtime.h>
#include <hip/hip_bf16.h>
#include <stdint.h>

// Int8Linear: y[m,n] = scale[n] * sum_k x[m,k]*w[n,k] + bias[n]
// Device dtypes: x fp32 [8192,4096]; w int32 [11008,4096] (|v|<=127);
// scale/bias fp32 [11008]; out fp32 [8192,11008].
// Round 11: r7 (best, 47.5% MfmaUtil) + ONE-PHASE-AHEAD fragment reads:
// every ds_read is issued >=1 phase before its consuming MFMA; pre-MFMA
// waits become counted lgkmcnt(4/8) instead of read-then-drain. Quadrants
// q00->q01->q11->q10; A-halves double-registered (aX/aY); B-half registers
// role-swap per tile (2-tile unrolled). All r7-validated pieces unchanged:
// XOR swizzle (0 conflicts), STG ledger, counted vmcnt(4), setprio, XCD
// swizzle, epilogue, prepass.

#define K_DIM 4096
#define N_DIM 11008
#define M_DIM 8192

typedef __attribute__((ext_vector_type(8))) __bf16 bf16x8;
typedef __attribute__((ext_vector_type(4))) float f32x4;
typedef __attribute__((ext_vector_type(4))) int i32x4;

#define SB0 __builtin_amdgcn_sched_barrier(0)

__device__ __forceinline__ void gload_lds16(const void* g, void* l) {
  __builtin_amdgcn_global_load_lds(
      (const __attribute__((address_space(1))) void*)g,
      (__attribute__((address_space(3))) void*)l, 16, 0, 0);
}

// ---------------- prepass conversions (validated round 3) ----------------

__global__ void __launch_bounds__(256) wconv_kernel(const int* __restrict__ w,
                                                    __bf16* __restrict__ o,
                                                    int n8) {
  int i = blockIdx.x * 256 + threadIdx.x;
  if (i >= n8) return;
  const i32x4* src = (const i32x4*)w;
  i32x4 v0 = src[2 * i];
  i32x4 v1 = src[2 * i + 1];
  bf16x8 r;
#pragma unroll
  for (int j = 0; j < 4; ++j) {
    r[j]     = (__bf16)(float)v0[j];
    r[j + 4] = (__bf16)(float)v1[j];
  }
  *((bf16x8*)o + i) = r;
}

__global__ void __launch_bounds__(256) xconv_kernel(const float* __restrict__ x,
                                                    __bf16* __restrict__ o,
                                                    int n8) {
  int i = blockIdx.x * 256 + threadIdx.x;
  if (i >= n8) return;
  const f32x4* src = (const f32x4*)x;
  f32x4 v0 = src[2 * i];
  f32x4 v1 = src[2 * i + 1];
  bf16x8 r;
#pragma unroll
  for (int j = 0; j < 4; ++j) {
    r[j]     = (__bf16)v0[j];
    r[j + 4] = (__bf16)v1[j];
  }
  *((bf16x8*)o + i) = r;
}

// ---------------- 256x256 BK=64 4-phase GEMM, read-ahead ----------------

#define BM 256
#define BN 256
#define BK 64
#define KT (K_DIM / BK)  /* 64 */
#define MT (M_DIM / BM)  /* 32 */
#define NT (N_DIM / BN)  /* 43 */
#define NBLK (MT * NT)   /* 1376 = 8*172 */
#define ABUF 16384       /* elems: one operand tile 256x64 */
#define BUFSZ 32768      /* elems: A+B per buffer = 64 KiB */

template <int RH, int CH>
__device__ __forceinline__ void mfma_quad(const bf16x8 aF[8],
                                          const bf16x8 bF[4],
                                          f32x4 acc[8][4]) {
  __builtin_amdgcn_s_setprio(1);
#pragma unroll
  for (int mf = 0; mf < 4; ++mf)
#pragma unroll
    for (int nf = 0; nf < 2; ++nf)
#pragma unroll
      for (int ks = 0; ks < 2; ++ks)
        acc[RH * 4 + mf][CH * 2 + nf] = __builtin_amdgcn_mfma_f32_16x16x32_bf16(
            aF[mf * 2 + ks], bF[nf * 2 + ks], acc[RH * 4 + mf][CH * 2 + nf], 0,
            0, 0);
  __builtin_amdgcn_s_setprio(0);
}

__global__ void __launch_bounds__(512, 2) gemm256_kernel(
    const __bf16* __restrict__ Xb, const __bf16* __restrict__ Wb,
    const float* __restrict__ scale, const float* __restrict__ bias,
    float* __restrict__ out) {
  __shared__ __align__(16) __bf16 lds[2 * BUFSZ];  // 128 KiB

  const int tid = threadIdx.x;
  const int lane = tid & 63;
  const int wv = tid >> 6;  // 0..7
  const int wr = wv >> 2;   // 0..1 (M half: 128 rows)
  const int wc = wv & 3;    // 0..3 (N quarter: 64 cols)

  // T1: bijective XCD swizzle (1376 = 8*172)
  const int lid = blockIdx.x;
  const int swz = (lid & 7) * (NBLK / 8) + (lid >> 3);
  const int tm = swz / NT;
  const int tn = swz - tm * NT;
  const size_t m0 = (size_t)tm * BM;
  const size_t n0 = (size_t)tn * BN;

  // staging (r7-validated): wave wv covers rows [R0+wv*8, R0+wv*8+8).
  // LDS[R][s] holds global k-chunk (s ^ (R&7)) via inverse-swizzled source.
  const int srow = tid >> 3;  // 0..63
  const int gchunk = (tid & 7) ^ (srow & 7);
  const size_t gOff = (size_t)srow * K_DIM + gchunk * 8;
  const int ldsWv = wv * 512;  // wave-uniform elem offset
  const __bf16* GA = Xb + m0 * K_DIM;
  const __bf16* GB = Wb + n0 * K_DIM;

#define STG(LP, OPB, R0, G, TS)                                      \
  gload_lds16((G) + (size_t)(R0) * K_DIM + (size_t)(TS) * BK + gOff, \
              &lds[(LP) * BUFSZ + (OPB) + (R0) * 64 + ldsWv])

  // fragment reads (swizzled): slot = (ks*4+kg) ^ (fr&7)
  const int fr = lane & 15;
  const int kg = lane >> 4;
  const int sw = fr & 7;
  const int aBase = (wr * 128 + fr) * 64;
  const int bBase = ABUF + (wc * 64 + fr) * 64;
  const int s0 = ((0 * 4 + kg) ^ sw) * 8;
  const int s1 = ((1 * 4 + kg) ^ sw) * 8;

#define RDA(LP, RF, KS) \
  (*(const bf16x8*)&lds[(LP)*BUFSZ + aBase + (RF)*1024 + ((KS) ? s1 : s0)])
#define RDB(LP, CF, KS) \
  (*(const bf16x8*)&lds[(LP)*BUFSZ + bBase + (CF)*1024 + ((KS) ? s1 : s0)])

  f32x4 acc[8][4];
#pragma unroll
  for (int m = 0; m < 8; ++m)
#pragma unroll
    for (int n = 0; n < 4; ++n) acc[m][n] = (f32x4){0.f, 0.f, 0.f, 0.f};

  // regs: aX/aY = A halves; B0R/B1R roles alternate per tile (bP/bQ).
  bf16x8 aX[8], aY[8], bP[4], bQ[4];

  // ---- prologue: stage A(0),B(0) -> buf0; B(1) -> buf1 (newest 4).
  STG(0, 0, 0, GA, 0);      STG(0, 0, 64, GA, 0);
  STG(0, 0, 128, GA, 0);    STG(0, 0, 192, GA, 0);
  STG(0, ABUF, 0, GB, 0);   STG(0, ABUF, 64, GB, 0);
  STG(0, ABUF, 128, GB, 0); STG(0, ABUF, 192, GB, 0);
  STG(1, ABUF, 0, GB, 1);   STG(1, ABUF, 64, GB, 1);
  STG(1, ABUF, 128, GB, 1); STG(1, ABUF, 192, GB, 1);
  asm volatile("s_waitcnt vmcnt(4)" ::: "memory");  // A(0),B(0) landed
  SB0;
  __builtin_amdgcn_s_barrier();
  // pre-read tile-0 operands for q00 (consumed in P0 after lgkmcnt(4))
#pragma unroll
  for (int rf = 0; rf < 4; ++rf) {
    aX[rf * 2] = RDA(0, rf, 0);
    aX[rf * 2 + 1] = RDA(0, rf, 1);
  }
#pragma unroll
  for (int cf = 0; cf < 2; ++cf) {
    bP[cf * 2] = RDB(0, cf, 0);
    bP[cf * 2 + 1] = RDB(0, cf, 1);
  }

  // tile body. B0R holds B0(T) at entry; B0(T+1) is loaded into B1R at P3
  // (roles swap each tile -> 2-tile unrolled loop).
#define TILE_BODY(B0R, B1R, T)                                              \
  do {                                                                      \
    const int p = (T) & 1;                                                  \
    const int np = p ^ 1;                                                   \
    const bool stA = (T) + 1 < KT;                                          \
    const bool stB = (T) + 2 < KT;                                          \
    /* P0: rd B1(T); stage A-h0(T+1); lgkm(4); q00(aX,B0R) */               \
    _Pragma("unroll") for (int cf = 0; cf < 2; ++cf) {                      \
      B1R[cf * 2] = RDB(p, 2 + cf, 0);                                      \
      B1R[cf * 2 + 1] = RDB(p, 2 + cf, 1);                                  \
    }                                                                       \
    if (stA) { STG(np, 0, 0, GA, (T) + 1); STG(np, 0, 64, GA, (T) + 1); }   \
    SB0;                                                                    \
    __builtin_amdgcn_s_barrier();                                           \
    asm volatile("s_waitcnt lgkmcnt(4)" ::: "memory");                      \
    SB0;                                                                    \
    mfma_quad<0, 0>(aX, B0R, acc);                                          \
    SB0;                                                                    \
    __builtin_amdgcn_s_barrier();                                           \
    /* P1: rd A1(T)->aY; stage A-h1(T+1); lgkm(8); q01(aX,B1R) */           \
    _Pragma("unroll") for (int rf = 0; rf < 4; ++rf) {                      \
      aY[rf * 2] = RDA(p, 4 + rf, 0);                                       \
      aY[rf * 2 + 1] = RDA(p, 4 + rf, 1);                                   \
    }                                                                       \
    if (stA) { STG(np, 0, 128, GA, (T) + 1); STG(np, 0, 192, GA, (T) + 1); }\
    SB0;                                                                    \
    __builtin_amdgcn_s_barrier();                                           \
    asm volatile("s_waitcnt lgkmcnt(8)" ::: "memory");                      \
    SB0;                                                                    \
    mfma_quad<0, 1>(aX, B1R, acc);                                          \
    SB0;                                                                    \
    __builtin_amdgcn_s_barrier();                                           \
    /* P2: stage B-h0(T+2); lgkm(0); q11(aY,B1R) */                         \
    if (stB) {                                                              \
      STG(p, ABUF, 0, GB, (T) + 2); STG(p, ABUF, 64, GB, (T) + 2);          \
    }                                                                       \
    SB0;                                                                    \
    __builtin_amdgcn_s_barrier();                                           \
    asm volatile("s_waitcnt lgkmcnt(0)" ::: "memory");                      \
    SB0;                                                                    \
    mfma_quad<1, 1>(aY, B1R, acc);                                          \
    SB0;                                                                    \
    __builtin_amdgcn_s_barrier();                                           \
    /* P3: stage B-h1(T+2); fence; bar; rd aX=A0(T+1),B1R=B0(T+1);          \
       q10(aY,B0R) covers the reads */                                      \
    if (stB) {                                                              \
      STG(p, ABUF, 128, GB, (T) + 2); STG(p, ABUF, 192, GB, (T) + 2);       \
    }                                                                       \
    SB0;                                                                    \
    if (stA) {                                                              \
      if (stB)                                                              \
        asm volatile("s_waitcnt vmcnt(4)" ::: "memory");                    \
      else                                                                  \
        asm volatile("s_waitcnt vmcnt(0)" ::: "memory");                    \
      SB0;                                                                  \
      __builtin_amdgcn_s_barrier();                                         \
      _Pragma("unroll") for (int rf = 0; rf < 4; ++rf) {                    \
        aX[rf * 2] = RDA(np, rf, 0);                                        \
        aX[rf * 2 + 1] = RDA(np, rf, 1);                                    \
      }                                                                     \
      _Pragma("unroll") for (int cf = 0; cf < 2; ++cf) {                    \
        B1R[cf * 2] = RDB(np, cf, 0);                                       \
        B1R[cf * 2 + 1] = RDB(np, cf, 1);                                   \
      }                                                                     \
      SB0;                                                                  \
      mfma_quad<1, 0>(aY, B0R, acc);                                        \
      SB0;                                                                  \
      __builtin_amdgcn_s_barrier();                                         \
    } else {                                                                \
      mfma_quad<1, 0>(aY, B0R, acc);                                        \
    }                                                                       \
  } while (0)

  for (int t = 0; t < KT; t += 2) {
    TILE_BODY(bP, bQ, t);
    TILE_BODY(bQ, bP, t + 1);
  }
#undef TILE_BODY

  // ---- epilogue: C/D layout col=lane&15, row=(lane>>4)*4+reg ----
  const int cc = lane & 15;
  const int rr = (lane >> 4) * 4;
#pragma unroll
  for (int nf = 0; nf < 4; ++nf) {
    const int col = (int)n0 + wc * 64 + nf * 16 + cc;
    const float sc = scale[col];
    const float bi = bias[col];
#pragma unroll
    for (int mf = 0; mf < 8; ++mf) {
      const size_t rowb = m0 + wr * 128 + mf * 16 + rr;
#pragma unroll
      for (int r = 0; r < 4; ++r) {
        out[(rowb + r) * N_DIM + col] = acc[mf][nf][r] * sc + bi;
      }
    }
  }
#undef STG
#undef RDA
#undef RDB
}

// ---------------- fallback 128x128 kernel (round-3 validated) ----------------

#define FBM 128
#define FBN 128
#define FBK 32
#define FNT (N_DIM / FBN) /* 86 */
#define FMT (M_DIM / FBM) /* 64 */

__device__ __forceinline__ bf16x8 cvt8f(f32x4 a, f32x4 b) {
  bf16x8 h;
#pragma unroll
  for (int j = 0; j < 4; ++j) {
    h[j] = (__bf16)a[j];
    h[j + 4] = (__bf16)b[j];
  }
  return h;
}

__device__ __forceinline__ bf16x8 cvt8i(i32x4 a, i32x4 b) {
  bf16x8 h;
#pragma unroll
  for (int j = 0; j < 4; ++j) {
    h[j] = (__bf16)(float)a[j];
    h[j + 4] = (__bf16)(float)b[j];
  }
  return h;
}

template <int MODE>  // 1: W preconv; 2: no workspace
__global__ void __launch_bounds__(256, 2) gemm_fb_kernel(
    const float* __restrict__ X, const __bf16* __restrict__ Wb,
    const int* __restrict__ Wq, const float* __restrict__ scale,
    const float* __restrict__ bias, float* __restrict__ out) {
  __shared__ __align__(16) __bf16 As[FBM * FBK];
  __shared__ __align__(16) __bf16 Bs[FBN * FBK];

  const int tid = threadIdx.x;
  const int lane = tid & 63;
  const int wv = tid >> 6;

  const int lid = blockIdx.x;
  const int swz = (lid & 7) * ((FMT * FNT) >> 3) + (lid >> 3);
  const int tm = swz / FNT;
  const int tn = swz - tm * FNT;
  const int m0 = tm * FBM;
  const int n0 = tn * FBN;

  const int e0 = wv * 512 + lane * 8;
  const int e1 = e0 + 2048;
  const int r0 = e0 >> 5, c0 = e0 & 31;
  const int r1 = e1 >> 5, c1 = e1 & 31;

  f32x4 acc[4][4];
#pragma unroll
  for (int m = 0; m < 4; ++m)
#pragma unroll
    for (int n = 0; n < 4; ++n) acc[m][n] = (f32x4){0.f, 0.f, 0.f, 0.f};

  const int wm = (wv >> 1) * 64;
  const int wn = (wv & 1) * 64;
  const int fr = lane & 15;
  const int kc = (lane >> 4) * 8;

  const float* srcAf0 = X + (size_t)(m0 + r0) * K_DIM + c0;
  const float* srcAf1 = X + (size_t)(m0 + r1) * K_DIM + c1;
  const __bf16* srcBb0 = Wb + (size_t)(n0 + r0) * K_DIM + c0;
  const __bf16* srcBb1 = Wb + (size_t)(n0 + r1) * K_DIM + c1;
  const int* srcQ0 = Wq + (size_t)(n0 + r0) * K_DIM + c0;
  const int* srcQ1 = Wq + (size_t)(n0 + r1) * K_DIM + c1;

  for (int k0 = 0; k0 < K_DIM; k0 += FBK) {
    f32x4 a0 = *(const f32x4*)(srcAf0 + k0);
    f32x4 a1 = *(const f32x4*)(srcAf0 + k0 + 4);
    f32x4 a2 = *(const f32x4*)(srcAf1 + k0);
    f32x4 a3 = *(const f32x4*)(srcAf1 + k0 + 4);
    if constexpr (MODE == 1) {
      gload_lds16(srcBb0 + k0, &Bs[e0]);
      gload_lds16(srcBb1 + k0, &Bs[e1]);
    } else {
      i32x4 q0 = *(const i32x4*)(srcQ0 + k0);
      i32x4 q1 = *(const i32x4*)(srcQ0 + k0 + 4);
      i32x4 q2 = *(const i32x4*)(srcQ1 + k0);
      i32x4 q3 = *(const i32x4*)(srcQ1 + k0 + 4);
      *(bf16x8*)&Bs[e0] = cvt8i(q0, q1);
      *(bf16x8*)&Bs[e1] = cvt8i(q2, q3);
    }
    *(bf16x8*)&As[e0] = cvt8f(a0, a1);
    *(bf16x8*)&As[e1] = cvt8f(a2, a3);
    __syncthreads();

    bf16x8 a[4], b[4];
#pragma unroll
    for (int m = 0; m < 4; ++m)
      a[m] = *(const bf16x8*)&As[(wm + m * 16 + fr) * FBK + kc];
#pragma unroll
    for (int n = 0; n < 4; ++n)
      b[n] = *(const bf16x8*)&Bs[(wn + n * 16 + fr) * FBK + kc];
#pragma unroll
    for (int m = 0; m < 4; ++m)
#pragma unroll
      for (int n = 0; n < 4; ++n)
        acc[m][n] = __builtin_amdgcn_mfma_f32_16x16x32_bf16(a[m], b[n],
                                                            acc[m][n], 0, 0, 0);
    __syncthreads();
  }

  const int cc = lane & 15;
  const int rr = (lane >> 4) * 4;
#pragma unroll
  for (int n = 0; n < 4; ++n) {
    const int col = n0 + wn + n * 16 + cc;
    const float sc = scale[col];
    const float bi = bias[col];
#pragma unroll
    for (int m = 0; m < 4; ++m) {
      const int rowb = m0 + wm + m * 16 + rr;
#pragma unroll
      for (int r = 0; r < 4; ++r) {
        out[(size_t)(rowb + r) * N_DIM + col] = acc[m][n][r] * sc + bi;
      }
    }
  }
}

// ---------------- launch ----------------

extern "C" void kernel_launch(void* const* d_in, const int* in_sizes, int n_in,
                              void* d_out, int out_size, void* d_ws, size_t ws_size,
                              hipStream_t stream) {
  const float* X = (const float*)d_in[0];
  const int* Wq = (const int*)d_in[1];
  const float* scale = (const float*)d_in[2];
  const float* bias = (const float*)d_in[3];
  float* out = (float*)d_out;

  const size_t wbytes = (size_t)N_DIM * K_DIM * sizeof(__bf16);  // 90,177,536
  const size_t xbytes = (size_t)M_DIM * K_DIM * sizeof(__bf16);  // 67,108,864
  const int n8w = (N_DIM * K_DIM) / 8;
  const int n8x = (M_DIM * K_DIM) / 8;

  if (ws_size >= wbytes + xbytes) {
    __bf16* Wb = (__bf16*)d_ws;
    __bf16* Xb = (__bf16*)((char*)d_ws + wbytes);
    wconv_kernel<<<dim3((n8w + 255) / 256), dim3(256), 0, stream>>>(Wq, Wb, n8w);
    xconv_kernel<<<dim3((n8x + 255) / 256), dim3(256), 0, stream>>>(X, Xb, n8x);
    gemm256_kernel<<<dim3(NBLK), dim3(512), 0, stream>>>(Xb, Wb, scale, bias, out);
  } else if (ws_size >= wbytes) {
    __bf16* Wb = (__bf16*)d_ws;
    wconv_kernel<<<dim3((n8w + 255) / 256), dim3(256), 0, stream>>>(Wq, Wb, n8w);
    gemm_fb_kernel<1><<<dim3(FMT * FNT), dim3(256), 0, stream>>>(
        X, Wb, Wq, scale, bias, out);
  } else {
    gemm_fb_kernel<2><<<dim3(FMT * FNT), dim3(256), 0, stream>>>(
        X, nullptr, Wq, scale, bias, out);
  }
}

// Round 12
// 1174.252 us; speedup vs baseline: 1.2940x; 1.2940x over previous
//
#include <hip/hip_runtime.h>
#include <hip/hip_bf16.h>
#include <stdint.h>

// Int8Linear: y[m,n] = scale[n] * sum_k x[m,k]*w[n,k] + bias[n]
// Device dtypes: x fp32 [8192,4096]; w int32 [11008,4096] (|v|<=127);
// scale/bias fp32 [11008]; out fp32 [8192,11008].
// Round 12: LDS-pipe shrink. Prepass permutes W -> bf16 FRAGMENT-ORDER
// (8KB segments per (ntile,wc,t): lane l reads frag f at base+f*1KB+l*16B,
// perfectly coalesced). GEMM: A staged in LDS (r7-validated swizzle, dbuf-2,
// 64 KiB), B loaded global->reg coalesced from LLC-resident Wfrag (no LDS,
// no barrier coupling). tm-fastest raster for B-panel L2 reuse. r8-style
// free inner schedule, 1 barrier/tile. LDS reads/tile: 192 -> 128.

#define K_DIM 4096
#define N_DIM 11008
#define M_DIM 8192

typedef __attribute__((ext_vector_type(8))) __bf16 bf16x8;
typedef __attribute__((ext_vector_type(4))) float f32x4;
typedef __attribute__((ext_vector_type(4))) int i32x4;

#define SB0 __builtin_amdgcn_sched_barrier(0)

__device__ __forceinline__ void gload_lds16(const void* g, void* l) {
  __builtin_amdgcn_global_load_lds(
      (const __attribute__((address_space(1))) void*)g,
      (__attribute__((address_space(3))) void*)l, 16, 0, 0);
}

// ---------------- prepass conversions ----------------

// W int32 -> bf16 row-major (fallback path only).
__global__ void __launch_bounds__(256) wconv_kernel(const int* __restrict__ w,
                                                    __bf16* __restrict__ o,
                                                    int n8) {
  int i = blockIdx.x * 256 + threadIdx.x;
  if (i >= n8) return;
  const i32x4* src = (const i32x4*)w;
  i32x4 v0 = src[2 * i];
  i32x4 v1 = src[2 * i + 1];
  bf16x8 r;
#pragma unroll
  for (int j = 0; j < 4; ++j) {
    r[j]     = (__bf16)(float)v0[j];
    r[j + 4] = (__bf16)(float)v1[j];
  }
  *((bf16x8*)o + i) = r;
}

// W int32 -> bf16 FRAGMENT-ORDER: u = ((((ntile*4+wc)*64+t)*8)+f)*64 + l
// holds 8 bf16 = W[n][k..k+7] with n = ntile*256+wc*64+(f>>1)*16+(l&15),
// k = t*64+(f&1)*32+(l>>4)*8.  (bijection over [11008]x[4096/8])
__global__ void __launch_bounds__(256) wfrag_kernel(const int* __restrict__ w,
                                                    __bf16* __restrict__ o,
                                                    int n8) {
  int u = blockIdx.x * 256 + threadIdx.x;
  if (u >= n8) return;
  const int l = u & 63;
  const int f = (u >> 6) & 7;
  const int seg = u >> 9;   // (ntile*4+wc)*64 + t
  const int t = seg & 63;
  const int q = seg >> 6;   // ntile*4 + wc
  const int n = (q >> 2) * 256 + (q & 3) * 64 + (f >> 1) * 16 + (l & 15);
  const int k = t * 64 + (f & 1) * 32 + (l >> 4) * 8;
  const int* src = w + (size_t)n * K_DIM + k;
  i32x4 v0 = *(const i32x4*)src;
  i32x4 v1 = *(const i32x4*)(src + 4);
  bf16x8 r;
#pragma unroll
  for (int j = 0; j < 4; ++j) {
    r[j]     = (__bf16)(float)v0[j];
    r[j + 4] = (__bf16)(float)v1[j];
  }
  *((bf16x8*)o + u) = r;
}

__global__ void __launch_bounds__(256) xconv_kernel(const float* __restrict__ x,
                                                    __bf16* __restrict__ o,
                                                    int n8) {
  int i = blockIdx.x * 256 + threadIdx.x;
  if (i >= n8) return;
  const f32x4* src = (const f32x4*)x;
  f32x4 v0 = src[2 * i];
  f32x4 v1 = src[2 * i + 1];
  bf16x8 r;
#pragma unroll
  for (int j = 0; j < 4; ++j) {
    r[j]     = (__bf16)v0[j];
    r[j + 4] = (__bf16)v1[j];
  }
  *((bf16x8*)o + i) = r;
}

// ---------------- 256x256 BK=64 GEMM: A-in-LDS, B-from-fragments ----------------

#define BM 256
#define BN 256
#define BK 64
#define KT (K_DIM / BK)  /* 64 */
#define MT (M_DIM / BM)  /* 32 */
#define NT (N_DIM / BN)  /* 43 */
#define NBLK (MT * NT)   /* 1376 = 8*172 */
#define ATILE 16384      /* elems: A tile 256x64 */

__global__ void __launch_bounds__(512, 2) gemmAB_kernel(
    const __bf16* __restrict__ Xb, const __bf16* __restrict__ Wf,
    const float* __restrict__ scale, const float* __restrict__ bias,
    float* __restrict__ out) {
  __shared__ __align__(16) __bf16 lds[2 * ATILE];  // 64 KiB (A dbuf only)

  const int tid = threadIdx.x;
  const int lane = tid & 63;
  const int wv = tid >> 6;  // 0..7
  const int wr = wv >> 2;   // 0..1 (M half: 128 rows)
  const int wc = wv & 3;    // 0..3 (N quarter: 64 cols)

  // XCD swizzle + tm-FASTEST raster (B-panel L2 reuse): 1376 = 43 tn x 32 tm
  const int lid = blockIdx.x;
  const int swz = (lid & 7) * (NBLK / 8) + (lid >> 3);
  const int tn = swz >> 5;   // 0..42
  const int tm = swz & 31;   // 0..31
  const size_t m0 = (size_t)tm * BM;
  const size_t n0 = (size_t)tn * BN;

  // ---- A staging (r7-validated): LDS[row][s] holds k-chunk s^(row&7) via
  // inverse-swizzled per-lane global source + wave-uniform LDS base.
  const int srow = tid >> 3;  // 0..63
  const int gchunk = (tid & 7) ^ (srow & 7);
  const size_t gOff = (size_t)srow * K_DIM + gchunk * 8;
  const int ldsWv = wv * 512;
  const __bf16* GA = Xb + m0 * K_DIM;

#define STGA(LP, R0, TS)                                             \
  gload_lds16(GA + (size_t)(R0) * K_DIM + (size_t)(TS) * BK + gOff,  \
              &lds[(LP) * ATILE + (R0) * 64 + ldsWv])

  // ---- A fragment reads (swizzled): slot = (ks*4+kg) ^ (fr&7) ----
  const int fr = lane & 15;
  const int kg = lane >> 4;
  const int sw = fr & 7;
  const int aBase = (wr * 128 + fr) * 64;
  const int s0 = ((0 * 4 + kg) ^ sw) * 8;
  const int s1 = ((1 * 4 + kg) ^ sw) * 8;

#define RDA(LP, RF, KS) \
  (*(const bf16x8*)&lds[(LP)*ATILE + aBase + (RF)*1024 + ((KS) ? s1 : s0)])

  // ---- B fragment-order base: segment (tn,wc,t) at ((tn*4+wc)*64+t)*4096
  const __bf16* GBF =
      Wf + ((size_t)(tn * 4 + wc)) * 64 * 4096 + (size_t)lane * 8;

  f32x4 acc[8][4];
#pragma unroll
  for (int m = 0; m < 8; ++m)
#pragma unroll
    for (int n = 0; n < 4; ++n) acc[m][n] = (f32x4){0.f, 0.f, 0.f, 0.f};

  // ---- prologue: stage A(0) into buffer 0 ----
  STGA(0, 0, 0);
  STGA(0, 64, 0);
  STGA(0, 128, 0);
  STGA(0, 192, 0);
  asm volatile("s_waitcnt vmcnt(0)" ::: "memory");
  SB0;
  __builtin_amdgcn_s_barrier();

  for (int t = 0; t < KT; ++t) {
    const int p = t & 1;
    const int np = p ^ 1;

    // 1) issue next-tile A staging first (4 DMAs), pinned before compute.
    if (t + 1 < KT) {
      STGA(np, 0, t + 1);
      STGA(np, 64, t + 1);
      STGA(np, 128, t + 1);
      STGA(np, 192, t + 1);
    }
    SB0;

    // 2) B fragments: coalesced global->reg (1KB per load, LLC-resident).
    const __bf16* gb = GBF + (size_t)t * 4096;
    bf16x8 b[8];
#pragma unroll
    for (int f = 0; f < 8; ++f) b[f] = *(const bf16x8*)(gb + f * 512);

    // 3) A reads + MFMA, compiler-scheduled (counted lgkm/vmcnt waits).
#pragma unroll
    for (int mf = 0; mf < 8; ++mf) {
      bf16x8 a0 = RDA(p, mf, 0);
      bf16x8 a1 = RDA(p, mf, 1);
#pragma unroll
      for (int nf = 0; nf < 4; ++nf) {
        acc[mf][nf] = __builtin_amdgcn_mfma_f32_16x16x32_bf16(
            a0, b[nf * 2], acc[mf][nf], 0, 0, 0);
        acc[mf][nf] = __builtin_amdgcn_mfma_f32_16x16x32_bf16(
            a1, b[nf * 2 + 1], acc[mf][nf], 0, 0, 0);
      }
    }

    // 4) tile end: own reads done (lgkm), staging landed (vmcnt, issued
    //    ~2400 cyc ago), then the single WAR/RAW barrier.
    asm volatile("s_waitcnt lgkmcnt(0)" ::: "memory");
    asm volatile("s_waitcnt vmcnt(0)" ::: "memory");
    __builtin_amdgcn_s_barrier();
  }

  // ---- epilogue: C/D layout col=lane&15, row=(lane>>4)*4+reg ----
  const int cc = lane & 15;
  const int rr = (lane >> 4) * 4;
#pragma unroll
  for (int nf = 0; nf < 4; ++nf) {
    const int col = (int)n0 + wc * 64 + nf * 16 + cc;
    const float sc = scale[col];
    const float bi = bias[col];
#pragma unroll
    for (int mf = 0; mf < 8; ++mf) {
      const size_t rowb = m0 + wr * 128 + mf * 16 + rr;
#pragma unroll
      for (int r = 0; r < 4; ++r) {
        out[(rowb + r) * N_DIM + col] = acc[mf][nf][r] * sc + bi;
      }
    }
  }
#undef STGA
#undef RDA
}

// ---------------- fallback 128x128 kernel (round-3 validated) ----------------

#define FBM 128
#define FBN 128
#define FBK 32
#define FNT (N_DIM / FBN) /* 86 */
#define FMT (M_DIM / FBM) /* 64 */

__device__ __forceinline__ bf16x8 cvt8f(f32x4 a, f32x4 b) {
  bf16x8 h;
#pragma unroll
  for (int j = 0; j < 4; ++j) {
    h[j] = (__bf16)a[j];
    h[j + 4] = (__bf16)b[j];
  }
  return h;
}

__device__ __forceinline__ bf16x8 cvt8i(i32x4 a, i32x4 b) {
  bf16x8 h;
#pragma unroll
  for (int j = 0; j < 4; ++j) {
    h[j] = (__bf16)(float)a[j];
    h[j + 4] = (__bf16)(float)b[j];
  }
  return h;
}

template <int MODE>  // 1: W preconv row-major; 2: no workspace
__global__ void __launch_bounds__(256, 2) gemm_fb_kernel(
    const float* __restrict__ X, const __bf16* __restrict__ Wb,
    const int* __restrict__ Wq, const float* __restrict__ scale,
    const float* __restrict__ bias, float* __restrict__ out) {
  __shared__ __align__(16) __bf16 As[FBM * FBK];
  __shared__ __align__(16) __bf16 Bs[FBN * FBK];

  const int tid = threadIdx.x;
  const int lane = tid & 63;
  const int wv = tid >> 6;

  const int lid = blockIdx.x;
  const int swz = (lid & 7) * ((FMT * FNT) >> 3) + (lid >> 3);
  const int tm = swz / FNT;
  const int tn = swz - tm * FNT;
  const int m0 = tm * FBM;
  const int n0 = tn * FBN;

  const int e0 = wv * 512 + lane * 8;
  const int e1 = e0 + 2048;
  const int r0 = e0 >> 5, c0 = e0 & 31;
  const int r1 = e1 >> 5, c1 = e1 & 31;

  f32x4 acc[4][4];
#pragma unroll
  for (int m = 0; m < 4; ++m)
#pragma unroll
    for (int n = 0; n < 4; ++n) acc[m][n] = (f32x4){0.f, 0.f, 0.f, 0.f};

  const int wm = (wv >> 1) * 64;
  const int wn = (wv & 1) * 64;
  const int fr = lane & 15;
  const int kc = (lane >> 4) * 8;

  const float* srcAf0 = X + (size_t)(m0 + r0) * K_DIM + c0;
  const float* srcAf1 = X + (size_t)(m0 + r1) * K_DIM + c1;
  const __bf16* srcBb0 = Wb + (size_t)(n0 + r0) * K_DIM + c0;
  const __bf16* srcBb1 = Wb + (size_t)(n0 + r1) * K_DIM + c1;
  const int* srcQ0 = Wq + (size_t)(n0 + r0) * K_DIM + c0;
  const int* srcQ1 = Wq + (size_t)(n0 + r1) * K_DIM + c1;

  for (int k0 = 0; k0 < K_DIM; k0 += FBK) {
    f32x4 a0 = *(const f32x4*)(srcAf0 + k0);
    f32x4 a1 = *(const f32x4*)(srcAf0 + k0 + 4);
    f32x4 a2 = *(const f32x4*)(srcAf1 + k0);
    f32x4 a3 = *(const f32x4*)(srcAf1 + k0 + 4);
    if constexpr (MODE == 1) {
      gload_lds16(srcBb0 + k0, &Bs[e0]);
      gload_lds16(srcBb1 + k0, &Bs[e1]);
    } else {
      i32x4 q0 = *(const i32x4*)(srcQ0 + k0);
      i32x4 q1 = *(const i32x4*)(srcQ0 + k0 + 4);
      i32x4 q2 = *(const i32x4*)(srcQ1 + k0);
      i32x4 q3 = *(const i32x4*)(srcQ1 + k0 + 4);
      *(bf16x8*)&Bs[e0] = cvt8i(q0, q1);
      *(bf16x8*)&Bs[e1] = cvt8i(q2, q3);
    }
    *(bf16x8*)&As[e0] = cvt8f(a0, a1);
    *(bf16x8*)&As[e1] = cvt8f(a2, a3);
    __syncthreads();

    bf16x8 a[4], b[4];
#pragma unroll
    for (int m = 0; m < 4; ++m)
      a[m] = *(const bf16x8*)&As[(wm + m * 16 + fr) * FBK + kc];
#pragma unroll
    for (int n = 0; n < 4; ++n)
      b[n] = *(const bf16x8*)&Bs[(wn + n * 16 + fr) * FBK + kc];
#pragma unroll
    for (int m = 0; m < 4; ++m)
#pragma unroll
      for (int n = 0; n < 4; ++n)
        acc[m][n] = __builtin_amdgcn_mfma_f32_16x16x32_bf16(a[m], b[n],
                                                            acc[m][n], 0, 0, 0);
    __syncthreads();
  }

  const int cc = lane & 15;
  const int rr = (lane >> 4) * 4;
#pragma unroll
  for (int n = 0; n < 4; ++n) {
    const int col = n0 + wn + n * 16 + cc;
    const float sc = scale[col];
    const float bi = bias[col];
#pragma unroll
    for (int m = 0; m < 4; ++m) {
      const int rowb = m0 + wm + m * 16 + rr;
#pragma unroll
      for (int r = 0; r < 4; ++r) {
        out[(size_t)(rowb + r) * N_DIM + col] = acc[m][n][r] * sc + bi;
      }
    }
  }
}

// ---------------- launch ----------------

extern "C" void kernel_launch(void* const* d_in, const int* in_sizes, int n_in,
                              void* d_out, int out_size, void* d_ws, size_t ws_size,
                              hipStream_t stream) {
  const float* X = (const float*)d_in[0];
  const int* Wq = (const int*)d_in[1];
  const float* scale = (const float*)d_in[2];
  const float* bias = (const float*)d_in[3];
  float* out = (float*)d_out;

  const size_t wbytes = (size_t)N_DIM * K_DIM * sizeof(__bf16);  // 90,177,536
  const size_t xbytes = (size_t)M_DIM * K_DIM * sizeof(__bf16);  // 67,108,864
  const int n8w = (N_DIM * K_DIM) / 8;  // 5,636,096
  const int n8x = (M_DIM * K_DIM) / 8;

  if (ws_size >= wbytes + xbytes) {
    __bf16* Wf = (__bf16*)d_ws;
    __bf16* Xb = (__bf16*)((char*)d_ws + wbytes);
    wfrag_kernel<<<dim3((n8w + 255) / 256), dim3(256), 0, stream>>>(Wq, Wf, n8w);
    xconv_kernel<<<dim3((n8x + 255) / 256), dim3(256), 0, stream>>>(X, Xb, n8x);
    gemmAB_kernel<<<dim3(NBLK), dim3(512), 0, stream>>>(Xb, Wf, scale, bias, out);
  } else if (ws_size >= wbytes) {
    __bf16* Wb = (__bf16*)d_ws;
    wconv_kernel<<<dim3((n8w + 255) / 256), dim3(256), 0, stream>>>(Wq, Wb, n8w);
    gemm_fb_kernel<1><<<dim3(FMT * FNT), dim3(256), 0, stream>>>(
        X, Wb, Wq, scale, bias, out);
  } else {
    gemm_fb_kernel<2><<<dim3(FMT * FNT), dim3(256), 0, stream>>>(
        X, nullptr, Wq, scale, bias, out);
  }
}

// Round 13
// 937.249 us; speedup vs baseline: 1.6212x; 1.2529x over previous
//
#include <hip/hip_runtime.h>
#include <hip/hip_bf16.h>
#include <stdint.h>

// Int8Linear: y[m,n] = scale[n] * sum_k x[m,k]*w[n,k] + bias[n]
// Device dtypes: x fp32 [8192,4096]; w int32 [11008,4096] (|v|<=127);
// scale/bias fp32 [11008]; out fp32 [8192,11008].
// Round 13: r12's fragment-order W (coalesced B glob->reg, validated) +
// r10's prefetch structure (B(t+1) into dbuf'd regs + stage A(t+1) at tile
// start; compute t with B already resident -> NO mid-tile vmcnt drain, which
// was r12's 2900-cyc/tile mistake). A-only LDS (64 KiB, r7-validated swizzle,
// 0 conflicts). 1 barrier/tile. tm-fastest raster, bijective XCD swizzle.

#define K_DIM 4096
#define N_DIM 11008
#define M_DIM 8192

typedef __attribute__((ext_vector_type(8))) __bf16 bf16x8;
typedef __attribute__((ext_vector_type(4))) float f32x4;
typedef __attribute__((ext_vector_type(4))) int i32x4;

#define SB0 __builtin_amdgcn_sched_barrier(0)

__device__ __forceinline__ void gload_lds16(const void* g, void* l) {
  __builtin_amdgcn_global_load_lds(
      (const __attribute__((address_space(1))) void*)g,
      (__attribute__((address_space(3))) void*)l, 16, 0, 0);
}

// ---------------- prepass conversions ----------------

// W int32 -> bf16 row-major (fallback path only).
__global__ void __launch_bounds__(256) wconv_kernel(const int* __restrict__ w,
                                                    __bf16* __restrict__ o,
                                                    int n8) {
  int i = blockIdx.x * 256 + threadIdx.x;
  if (i >= n8) return;
  const i32x4* src = (const i32x4*)w;
  i32x4 v0 = src[2 * i];
  i32x4 v1 = src[2 * i + 1];
  bf16x8 r;
#pragma unroll
  for (int j = 0; j < 4; ++j) {
    r[j]     = (__bf16)(float)v0[j];
    r[j + 4] = (__bf16)(float)v1[j];
  }
  *((bf16x8*)o + i) = r;
}

// W int32 -> bf16 FRAGMENT-ORDER (r12-validated): u = (((ntile*4+wc)*64+t)*8+f)*64+l
// holds W[n][k..k+7], n = ntile*256+wc*64+(f>>1)*16+(l&15),
// k = t*64+(f&1)*32+(l>>4)*8.
__global__ void __launch_bounds__(256) wfrag_kernel(const int* __restrict__ w,
                                                    __bf16* __restrict__ o,
                                                    int n8) {
  int u = blockIdx.x * 256 + threadIdx.x;
  if (u >= n8) return;
  const int l = u & 63;
  const int f = (u >> 6) & 7;
  const int seg = u >> 9;   // (ntile*4+wc)*64 + t
  const int t = seg & 63;
  const int q = seg >> 6;   // ntile*4 + wc
  const int n = (q >> 2) * 256 + (q & 3) * 64 + (f >> 1) * 16 + (l & 15);
  const int k = t * 64 + (f & 1) * 32 + (l >> 4) * 8;
  const int* src = w + (size_t)n * K_DIM + k;
  i32x4 v0 = *(const i32x4*)src;
  i32x4 v1 = *(const i32x4*)(src + 4);
  bf16x8 r;
#pragma unroll
  for (int j = 0; j < 4; ++j) {
    r[j]     = (__bf16)(float)v0[j];
    r[j + 4] = (__bf16)(float)v1[j];
  }
  *((bf16x8*)o + u) = r;
}

__global__ void __launch_bounds__(256) xconv_kernel(const float* __restrict__ x,
                                                    __bf16* __restrict__ o,
                                                    int n8) {
  int i = blockIdx.x * 256 + threadIdx.x;
  if (i >= n8) return;
  const f32x4* src = (const f32x4*)x;
  f32x4 v0 = src[2 * i];
  f32x4 v1 = src[2 * i + 1];
  bf16x8 r;
#pragma unroll
  for (int j = 0; j < 4; ++j) {
    r[j]     = (__bf16)v0[j];
    r[j + 4] = (__bf16)v1[j];
  }
  *((bf16x8*)o + i) = r;
}

// ---------------- 256x256 BK=64 GEMM: A-in-LDS, B-prefetched regs ----------------

#define BM 256
#define BN 256
#define BK 64
#define KT (K_DIM / BK)  /* 64 */
#define MT (M_DIM / BM)  /* 32 */
#define NT (N_DIM / BN)  /* 43 */
#define NBLK (MT * NT)   /* 1376 = 8*172 */
#define ATILE 16384      /* elems: A tile 256x64 */

__global__ void __launch_bounds__(512, 2) gemmAB_kernel(
    const __bf16* __restrict__ Xb, const __bf16* __restrict__ Wf,
    const float* __restrict__ scale, const float* __restrict__ bias,
    float* __restrict__ out) {
  __shared__ __align__(16) __bf16 lds[2 * ATILE];  // 64 KiB (A dbuf only)

  const int tid = threadIdx.x;
  const int lane = tid & 63;
  const int wv = tid >> 6;  // 0..7
  const int wr = wv >> 2;   // 0..1 (M half: 128 rows)
  const int wc = wv & 3;    // 0..3 (N quarter: 64 cols)

  // XCD swizzle + tm-fastest raster (B-panel L2 reuse): 1376 = 43 tn x 32 tm
  const int lid = blockIdx.x;
  const int swz = (lid & 7) * (NBLK / 8) + (lid >> 3);
  const int tn = swz >> 5;   // 0..42
  const int tm = swz & 31;   // 0..31
  const size_t m0 = (size_t)tm * BM;
  const size_t n0 = (size_t)tn * BN;

  // ---- A staging (r7-validated): LDS[row][s] holds k-chunk s^(row&7) via
  // inverse-swizzled per-lane global source + wave-uniform LDS base.
  const int srow = tid >> 3;  // 0..63
  const int gchunk = (tid & 7) ^ (srow & 7);
  const size_t gOff = (size_t)srow * K_DIM + gchunk * 8;
  const int ldsWv = wv * 512;
  const __bf16* GA = Xb + m0 * K_DIM;

#define STGA(LP, R0, TS)                                             \
  gload_lds16(GA + (size_t)(R0) * K_DIM + (size_t)(TS) * BK + gOff,  \
              &lds[(LP) * ATILE + (R0) * 64 + ldsWv])

  // ---- A fragment reads (swizzled): slot = (ks*4+kg) ^ (fr&7) ----
  const int fr = lane & 15;
  const int kg = lane >> 4;
  const int sw = fr & 7;
  const int aBase = (wr * 128 + fr) * 64;
  const int s0 = ((0 * 4 + kg) ^ sw) * 8;
  const int s1 = ((1 * 4 + kg) ^ sw) * 8;

#define RDA(LP, RF, KS) \
  (*(const bf16x8*)&lds[(LP)*ATILE + aBase + (RF)*1024 + ((KS) ? s1 : s0)])

  // ---- B fragment-order base: segment (tn,wc,t) at ((tn*4+wc)*64+t)*4096
  const __bf16* GBF =
      Wf + ((size_t)(tn * 4 + wc)) * 64 * 4096 + (size_t)lane * 8;

  f32x4 acc[8][4];
#pragma unroll
  for (int m = 0; m < 8; ++m)
#pragma unroll
    for (int n = 0; n < 4; ++n) acc[m][n] = (f32x4){0.f, 0.f, 0.f, 0.f};

  bf16x8 bX[8], bY[8];

  // ---- prologue: stage A(0); load B(0) frags; drain; barrier ----
  STGA(0, 0, 0);
  STGA(0, 64, 0);
  STGA(0, 128, 0);
  STGA(0, 192, 0);
#pragma unroll
  for (int f = 0; f < 8; ++f) bX[f] = *(const bf16x8*)(GBF + f * 512);
  asm volatile("s_waitcnt vmcnt(0)" ::: "memory");
  SB0;
  __builtin_amdgcn_s_barrier();

  // tile body: issue B(T+1)->BNXT + stage A(T+1); compute T (B resident,
  // A via compiler-counted lgkm); tile-end drain (issued ~4000cyc ago) + bar.
#define TILE_BODY(BCUR, BNXT, T)                                          \
  do {                                                                    \
    const int p = (T) & 1;                                                \
    const int np = p ^ 1;                                                 \
    if ((T) + 1 < KT) {                                                   \
      const __bf16* gb = GBF + (size_t)((T) + 1) * 4096;                  \
      _Pragma("unroll") for (int f = 0; f < 8; ++f)                       \
          BNXT[f] = *(const bf16x8*)(gb + f * 512);                       \
      STGA(np, 0, (T) + 1);                                               \
      STGA(np, 64, (T) + 1);                                              \
      STGA(np, 128, (T) + 1);                                             \
      STGA(np, 192, (T) + 1);                                             \
    }                                                                     \
    SB0;                                                                  \
    _Pragma("unroll") for (int mf = 0; mf < 8; ++mf) {                    \
      bf16x8 a0 = RDA(p, mf, 0);                                          \
      bf16x8 a1 = RDA(p, mf, 1);                                          \
      _Pragma("unroll") for (int nf = 0; nf < 4; ++nf) {                  \
        acc[mf][nf] = __builtin_amdgcn_mfma_f32_16x16x32_bf16(            \
            a0, BCUR[nf * 2], acc[mf][nf], 0, 0, 0);                      \
        acc[mf][nf] = __builtin_amdgcn_mfma_f32_16x16x32_bf16(            \
            a1, BCUR[nf * 2 + 1], acc[mf][nf], 0, 0, 0);                  \
      }                                                                   \
    }                                                                     \
    asm volatile("s_waitcnt lgkmcnt(0)" ::: "memory");                    \
    asm volatile("s_waitcnt vmcnt(0)" ::: "memory");                      \
    __builtin_amdgcn_s_barrier();                                         \
  } while (0)

  for (int t = 0; t < KT; t += 2) {
    TILE_BODY(bX, bY, t);
    TILE_BODY(bY, bX, t + 1);
  }
#undef TILE_BODY

  // ---- epilogue: C/D layout col=lane&15, row=(lane>>4)*4+reg ----
  const int cc = lane & 15;
  const int rr = (lane >> 4) * 4;
#pragma unroll
  for (int nf = 0; nf < 4; ++nf) {
    const int col = (int)n0 + wc * 64 + nf * 16 + cc;
    const float sc = scale[col];
    const float bi = bias[col];
#pragma unroll
    for (int mf = 0; mf < 8; ++mf) {
      const size_t rowb = m0 + wr * 128 + mf * 16 + rr;
#pragma unroll
      for (int r = 0; r < 4; ++r) {
        out[(rowb + r) * N_DIM + col] = acc[mf][nf][r] * sc + bi;
      }
    }
  }
#undef STGA
#undef RDA
}

// ---------------- fallback 128x128 kernel (round-3 validated) ----------------

#define FBM 128
#define FBN 128
#define FBK 32
#define FNT (N_DIM / FBN) /* 86 */
#define FMT (M_DIM / FBM) /* 64 */

__device__ __forceinline__ bf16x8 cvt8f(f32x4 a, f32x4 b) {
  bf16x8 h;
#pragma unroll
  for (int j = 0; j < 4; ++j) {
    h[j] = (__bf16)a[j];
    h[j + 4] = (__bf16)b[j];
  }
  return h;
}

__device__ __forceinline__ bf16x8 cvt8i(i32x4 a, i32x4 b) {
  bf16x8 h;
#pragma unroll
  for (int j = 0; j < 4; ++j) {
    h[j] = (__bf16)(float)a[j];
    h[j + 4] = (__bf16)(float)b[j];
  }
  return h;
}

template <int MODE>  // 1: W preconv row-major; 2: no workspace
__global__ void __launch_bounds__(256, 2) gemm_fb_kernel(
    const float* __restrict__ X, const __bf16* __restrict__ Wb,
    const int* __restrict__ Wq, const float* __restrict__ scale,
    const float* __restrict__ bias, float* __restrict__ out) {
  __shared__ __align__(16) __bf16 As[FBM * FBK];
  __shared__ __align__(16) __bf16 Bs[FBN * FBK];

  const int tid = threadIdx.x;
  const int lane = tid & 63;
  const int wv = tid >> 6;

  const int lid = blockIdx.x;
  const int swz = (lid & 7) * ((FMT * FNT) >> 3) + (lid >> 3);
  const int tm = swz / FNT;
  const int tn = swz - tm * FNT;
  const int m0 = tm * FBM;
  const int n0 = tn * FBN;

  const int e0 = wv * 512 + lane * 8;
  const int e1 = e0 + 2048;
  const int r0 = e0 >> 5, c0 = e0 & 31;
  const int r1 = e1 >> 5, c1 = e1 & 31;

  f32x4 acc[4][4];
#pragma unroll
  for (int m = 0; m < 4; ++m)
#pragma unroll
    for (int n = 0; n < 4; ++n) acc[m][n] = (f32x4){0.f, 0.f, 0.f, 0.f};

  const int wm = (wv >> 1) * 64;
  const int wn = (wv & 1) * 64;
  const int fr = lane & 15;
  const int kc = (lane >> 4) * 8;

  const float* srcAf0 = X + (size_t)(m0 + r0) * K_DIM + c0;
  const float* srcAf1 = X + (size_t)(m0 + r1) * K_DIM + c1;
  const __bf16* srcBb0 = Wb + (size_t)(n0 + r0) * K_DIM + c0;
  const __bf16* srcBb1 = Wb + (size_t)(n0 + r1) * K_DIM + c1;
  const int* srcQ0 = Wq + (size_t)(n0 + r0) * K_DIM + c0;
  const int* srcQ1 = Wq + (size_t)(n0 + r1) * K_DIM + c1;

  for (int k0 = 0; k0 < K_DIM; k0 += FBK) {
    f32x4 a0 = *(const f32x4*)(srcAf0 + k0);
    f32x4 a1 = *(const f32x4*)(srcAf0 + k0 + 4);
    f32x4 a2 = *(const f32x4*)(srcAf1 + k0);
    f32x4 a3 = *(const f32x4*)(srcAf1 + k0 + 4);
    if constexpr (MODE == 1) {
      gload_lds16(srcBb0 + k0, &Bs[e0]);
      gload_lds16(srcBb1 + k0, &Bs[e1]);
    } else {
      i32x4 q0 = *(const i32x4*)(srcQ0 + k0);
      i32x4 q1 = *(const i32x4*)(srcQ0 + k0 + 4);
      i32x4 q2 = *(const i32x4*)(srcQ1 + k0);
      i32x4 q3 = *(const i32x4*)(srcQ1 + k0 + 4);
      *(bf16x8*)&Bs[e0] = cvt8i(q0, q1);
      *(bf16x8*)&Bs[e1] = cvt8i(q2, q3);
    }
    *(bf16x8*)&As[e0] = cvt8f(a0, a1);
    *(bf16x8*)&As[e1] = cvt8f(a2, a3);
    __syncthreads();

    bf16x8 a[4], b[4];
#pragma unroll
    for (int m = 0; m < 4; ++m)
      a[m] = *(const bf16x8*)&As[(wm + m * 16 + fr) * FBK + kc];
#pragma unroll
    for (int n = 0; n < 4; ++n)
      b[n] = *(const bf16x8*)&Bs[(wn + n * 16 + fr) * FBK + kc];
#pragma unroll
    for (int m = 0; m < 4; ++m)
#pragma unroll
      for (int n = 0; n < 4; ++n)
        acc[m][n] = __builtin_amdgcn_mfma_f32_16x16x32_bf16(a[m], b[n],
                                                            acc[m][n], 0, 0, 0);
    __syncthreads();
  }

  const int cc = lane & 15;
  const int rr = (lane >> 4) * 4;
#pragma unroll
  for (int n = 0; n < 4; ++n) {
    const int col = n0 + wn + n * 16 + cc;
    const float sc = scale[col];
    const float bi = bias[col];
#pragma unroll
    for (int m = 0; m < 4; ++m) {
      const int rowb = m0 + wm + m * 16 + rr;
#pragma unroll
      for (int r = 0; r < 4; ++r) {
        out[(size_t)(rowb + r) * N_DIM + col] = acc[m][n][r] * sc + bi;
      }
    }
  }
}

// ---------------- launch ----------------

extern "C" void kernel_launch(void* const* d_in, const int* in_sizes, int n_in,
                              void* d_out, int out_size, void* d_ws, size_t ws_size,
                              hipStream_t stream) {
  const float* X = (const float*)d_in[0];
  const int* Wq = (const int*)d_in[1];
  const float* scale = (const float*)d_in[2];
  const float* bias = (const float*)d_in[3];
  float* out = (float*)d_out;

  const size_t wbytes = (size_t)N_DIM * K_DIM * sizeof(__bf16);  // 90,177,536
  const size_t xbytes = (size_t)M_DIM * K_DIM * sizeof(__bf16);  // 67,108,864
  const int n8w = (N_DIM * K_DIM) / 8;  // 5,636,096
  const int n8x = (M_DIM * K_DIM) / 8;

  if (ws_size >= wbytes + xbytes) {
    __bf16* Wf = (__bf16*)d_ws;
    __bf16* Xb = (__bf16*)((char*)d_ws + wbytes);
    wfrag_kernel<<<dim3((n8w + 255) / 256), dim3(256), 0, stream>>>(Wq, Wf, n8w);
    xconv_kernel<<<dim3((n8x + 255) / 256), dim3(256), 0, stream>>>(X, Xb, n8x);
    gemmAB_kernel<<<dim3(NBLK), dim3(512), 0, stream>>>(Xb, Wf, scale, bias, out);
  } else if (ws_size >= wbytes) {
    __bf16* Wb = (__bf16*)d_ws;
    wconv_kernel<<<dim3((n8w + 255) / 256), dim3(256), 0, stream>>>(Wq, Wb, n8w);
    gemm_fb_kernel<1><<<dim3(FMT * FNT), dim3(256), 0, stream>>>(
        X, Wb, Wq, scale, bias, out);
  } else {
    gemm_fb_kernel<2><<<dim3(FMT * FNT), dim3(256), 0, stream>>>(
        X, nullptr, Wq, scale, bias, out);
  }
}

// Round 14
// 821.502 us; speedup vs baseline: 1.8496x; 1.1409x over previous
//
#include <hip/hip_runtime.h>
#include <hip/hip_bf16.h>
#include <stdint.h>

// Int8Linear: y[m,n] = scale[n] * sum_k x[m,k]*w[n,k] + bias[n]
// Device dtypes: x fp32 [8192,4096]; w int32 [11008,4096] (|v|<=127);
// scale/bias fp32 [11008]; out fp32 [8192,11008].
// Round 14: r7 skeleton (best: 695us GEMM, 47.5% MfmaUtil, 0 conflicts)
// with the MFMA shape switched 16x16x32 -> 32x32x16 (u-bench 2382 vs 2075 TF,
// +15% matrix-pipe ceiling at identical LDS traffic and register totals).
// Identical staging ledger, vmcnt(4) stagger, 4-phase schedule with the same
// per-phase read counts (quadrant = 2 C-tiles of 32x32). Fragment maps:
// A/B: lane l -> row/col l&31, k=(l>>5)*8+j ; C/D: col=lane&31,
// row=(reg&3)+8*(reg>>2)+4*(lane>>5) (m74/m101-verified).

#define K_DIM 4096
#define N_DIM 11008
#define M_DIM 8192

typedef __attribute__((ext_vector_type(8))) __bf16 bf16x8;
typedef __attribute__((ext_vector_type(4))) float f32x4;
typedef __attribute__((ext_vector_type(16))) float f32x16;
typedef __attribute__((ext_vector_type(4))) int i32x4;

#define SB0 __builtin_amdgcn_sched_barrier(0)

__device__ __forceinline__ void gload_lds16(const void* g, void* l) {
  __builtin_amdgcn_global_load_lds(
      (const __attribute__((address_space(1))) void*)g,
      (__attribute__((address_space(3))) void*)l, 16, 0, 0);
}

// ---------------- prepass conversions (validated round 3) ----------------

__global__ void __launch_bounds__(256) wconv_kernel(const int* __restrict__ w,
                                                    __bf16* __restrict__ o,
                                                    int n8) {
  int i = blockIdx.x * 256 + threadIdx.x;
  if (i >= n8) return;
  const i32x4* src = (const i32x4*)w;
  i32x4 v0 = src[2 * i];
  i32x4 v1 = src[2 * i + 1];
  bf16x8 r;
#pragma unroll
  for (int j = 0; j < 4; ++j) {
    r[j]     = (__bf16)(float)v0[j];
    r[j + 4] = (__bf16)(float)v1[j];
  }
  *((bf16x8*)o + i) = r;
}

__global__ void __launch_bounds__(256) xconv_kernel(const float* __restrict__ x,
                                                    __bf16* __restrict__ o,
                                                    int n8) {
  int i = blockIdx.x * 256 + threadIdx.x;
  if (i >= n8) return;
  const f32x4* src = (const f32x4*)x;
  f32x4 v0 = src[2 * i];
  f32x4 v1 = src[2 * i + 1];
  bf16x8 r;
#pragma unroll
  for (int j = 0; j < 4; ++j) {
    r[j]     = (__bf16)v0[j];
    r[j + 4] = (__bf16)v1[j];
  }
  *((bf16x8*)o + i) = r;
}

// ---------------- 256x256 BK=64 4-phase GEMM, 32x32x16 MFMA ----------------

#define BM 256
#define BN 256
#define BK 64
#define KT (K_DIM / BK)  /* 64 */
#define MT (M_DIM / BM)  /* 32 */
#define NT (N_DIM / BN)  /* 43 */
#define NBLK (MT * NT)   /* 1376 = 8*172 */
#define ABUF 16384       /* elems: one operand tile 256x64 */
#define BUFSZ 32768      /* elems: A+B per buffer = 64 KiB */

// quadrant (RH, CH): C-tiles (mt = RH*2 + ml, nt = CH), ml in {0,1}.
// aF[ml*4+ks], bF[ks]. ks-outer order -> 2 independent acc chains.
template <int RH, int CH>
__device__ __forceinline__ void mfma_quad(const bf16x8 aF[8],
                                          const bf16x8 bF[4],
                                          f32x16 acc[4][2]) {
  __builtin_amdgcn_s_setprio(1);
#pragma unroll
  for (int ks = 0; ks < 4; ++ks)
#pragma unroll
    for (int ml = 0; ml < 2; ++ml)
      acc[RH * 2 + ml][CH] = __builtin_amdgcn_mfma_f32_32x32x16_bf16(
          aF[ml * 4 + ks], bF[ks], acc[RH * 2 + ml][CH], 0, 0, 0);
  __builtin_amdgcn_s_setprio(0);
}

__global__ void __launch_bounds__(512, 2) gemm256_kernel(
    const __bf16* __restrict__ Xb, const __bf16* __restrict__ Wb,
    const float* __restrict__ scale, const float* __restrict__ bias,
    float* __restrict__ out) {
  __shared__ __align__(16) __bf16 lds[2 * BUFSZ];  // 128 KiB

  const int tid = threadIdx.x;
  const int lane = tid & 63;
  const int wv = tid >> 6;  // 0..7
  const int wr = wv >> 2;   // 0..1 (M half: 128 rows)
  const int wc = wv & 3;    // 0..3 (N quarter: 64 cols)

  // T1: bijective XCD swizzle (1376 = 8*172)
  const int lid = blockIdx.x;
  const int swz = (lid & 7) * (NBLK / 8) + (lid >> 3);
  const int tm = swz / NT;
  const int tn = swz - tm * NT;
  const size_t m0 = (size_t)tm * BM;
  const size_t n0 = (size_t)tn * BN;

  // staging (r7-validated): wave wv covers rows [R0+wv*8, R0+wv*8+8).
  // LDS[R][s] holds global k-chunk (s ^ (R&7)) via inverse-swizzled source.
  const int srow = tid >> 3;  // 0..63
  const int gchunk = (tid & 7) ^ (srow & 7);
  const size_t gOff = (size_t)srow * K_DIM + gchunk * 8;
  const int ldsWv = wv * 512;  // wave-uniform elem offset
  const __bf16* GA = Xb + m0 * K_DIM;
  const __bf16* GB = Wb + n0 * K_DIM;

#define STG(LP, OPB, R0, G, TS)                                      \
  gload_lds16((G) + (size_t)(R0) * K_DIM + (size_t)(TS) * BK + gOff, \
              &lds[(LP) * BUFSZ + (OPB) + (R0) * 64 + ldsWv])

  // fragment reads (32x32 shape): lane l -> row base + (l&31),
  // chunk = ks*2 + (l>>5), slot = chunk ^ (row&7).  lanes 0..7 cover 8
  // distinct slots -> conflict-free per the model matching r7's zero count.
  const int r5 = lane & 31;
  const int hi = lane >> 5;
  const int sw5 = r5 & 7;
  int sK[4];
#pragma unroll
  for (int ks = 0; ks < 4; ++ks) sK[ks] = ((ks * 2 + hi) ^ sw5) * 8;
  const int aBase = (wr * 128 + r5) * 64;
  const int bBase = ABUF + (wc * 64 + r5) * 64;

#define RDA(LP, MT_, KS) \
  (*(const bf16x8*)&lds[(LP)*BUFSZ + aBase + (MT_)*2048 + sK[(KS)]])
#define RDB(LP, NT_, KS) \
  (*(const bf16x8*)&lds[(LP)*BUFSZ + bBase + (NT_)*2048 + sK[(KS)]])

  f32x16 acc[4][2];
#pragma unroll
  for (int m = 0; m < 4; ++m)
#pragma unroll
    for (int n = 0; n < 2; ++n)
#pragma unroll
      for (int j = 0; j < 16; ++j) acc[m][n][j] = 0.f;

  // ---- prologue (r7-identical): A(0),B(0)->buf0; B(1)->buf1; vmcnt(4) ----
  STG(0, ABUF, 0, GB, 0);   STG(0, ABUF, 64, GB, 0);
  STG(0, ABUF, 128, GB, 0); STG(0, ABUF, 192, GB, 0);
  STG(0, 0, 0, GA, 0);      STG(0, 0, 64, GA, 0);
  STG(0, 0, 128, GA, 0);    STG(0, 0, 192, GA, 0);
  STG(1, ABUF, 0, GB, 1);   STG(1, ABUF, 64, GB, 1);
  STG(1, ABUF, 128, GB, 1); STG(1, ABUF, 192, GB, 1);
  asm volatile("s_waitcnt vmcnt(4)" ::: "memory");
  SB0;
  __builtin_amdgcn_s_barrier();

  bf16x8 aF[8], aG[8], bA[4], bB[4];

  for (int t = 0; t < KT; ++t) {
    const int p = t & 1;
    const int np = p ^ 1;
    const bool stA = (t + 1 < KT);
    const bool stB = (t + 2 < KT);

    // ====== P0: read A mt0-1 (8) + B nt0 (4); stage Ah0(t+1); q(0,0) ======
#pragma unroll
    for (int ml = 0; ml < 2; ++ml)
#pragma unroll
      for (int ks = 0; ks < 4; ++ks) aF[ml * 4 + ks] = RDA(p, ml, ks);
#pragma unroll
    for (int ks = 0; ks < 4; ++ks) bA[ks] = RDB(p, 0, ks);
    if (stA) { STG(np, 0, 0, GA, t + 1); STG(np, 0, 64, GA, t + 1); }
    asm volatile("s_waitcnt lgkmcnt(8)" ::: "memory");
    SB0;
    __builtin_amdgcn_s_barrier();
    asm volatile("s_waitcnt lgkmcnt(0)" ::: "memory");
    SB0;
    mfma_quad<0, 0>(aF, bA, acc);
    SB0;
    __builtin_amdgcn_s_barrier();

    // ====== P1: read B nt1 (4); stage Ah1(t+1); q(0,1) ====================
#pragma unroll
    for (int ks = 0; ks < 4; ++ks) bB[ks] = RDB(p, 1, ks);
    if (stA) { STG(np, 0, 128, GA, t + 1); STG(np, 0, 192, GA, t + 1); }
    SB0;
    __builtin_amdgcn_s_barrier();
    asm volatile("s_waitcnt lgkmcnt(0)" ::: "memory");
    SB0;
    mfma_quad<0, 1>(aF, bB, acc);
    SB0;
    __builtin_amdgcn_s_barrier();

    // ====== P2: read A mt2-3 (8); stage Bh0(t+2); q(1,1) ==================
#pragma unroll
    for (int ml = 0; ml < 2; ++ml)
#pragma unroll
      for (int ks = 0; ks < 4; ++ks) aG[ml * 4 + ks] = RDA(p, 2 + ml, ks);
    if (stB) { STG(p, ABUF, 0, GB, t + 2); STG(p, ABUF, 64, GB, t + 2); }
    SB0;
    __builtin_amdgcn_s_barrier();
    asm volatile("s_waitcnt lgkmcnt(0)" ::: "memory");
    SB0;
    mfma_quad<1, 1>(aG, bB, acc);
    SB0;
    __builtin_amdgcn_s_barrier();

    // ====== P3: stage Bh1(t+2); q(1,0); counted fence; barrier ============
    if (stB) { STG(p, ABUF, 128, GB, t + 2); STG(p, ABUF, 192, GB, t + 2); }
    SB0;
    mfma_quad<1, 0>(aG, bA, acc);
    SB0;
    if (stB)
      asm volatile("s_waitcnt vmcnt(4)" ::: "memory");
    else
      asm volatile("s_waitcnt vmcnt(0)" ::: "memory");
    SB0;
    __builtin_amdgcn_s_barrier();
  }

  // ---- epilogue: 32x32 C/D layout (m74/m101): col = lane&31,
  // row = (reg&3) + 8*(reg>>2) + 4*(lane>>5) ----
#pragma unroll
  for (int nt = 0; nt < 2; ++nt) {
    const int col = (int)n0 + wc * 64 + nt * 32 + r5;
    const float sc = scale[col];
    const float bi = bias[col];
#pragma unroll
    for (int mt = 0; mt < 4; ++mt) {
      const size_t rowb = m0 + wr * 128 + mt * 32 + hi * 4;
#pragma unroll
      for (int rg = 0; rg < 16; ++rg) {
        const size_t row = rowb + (rg & 3) + 8 * (rg >> 2);
        out[row * N_DIM + col] = acc[mt][nt][rg] * sc + bi;
      }
    }
  }
#undef STG
#undef RDA
#undef RDB
}

// ---------------- fallback 128x128 kernel (round-3 validated) ----------------

#define FBM 128
#define FBN 128
#define FBK 32
#define FNT (N_DIM / FBN) /* 86 */
#define FMT (M_DIM / FBM) /* 64 */

__device__ __forceinline__ bf16x8 cvt8f(f32x4 a, f32x4 b) {
  bf16x8 h;
#pragma unroll
  for (int j = 0; j < 4; ++j) {
    h[j] = (__bf16)a[j];
    h[j + 4] = (__bf16)b[j];
  }
  return h;
}

__device__ __forceinline__ bf16x8 cvt8i(i32x4 a, i32x4 b) {
  bf16x8 h;
#pragma unroll
  for (int j = 0; j < 4; ++j) {
    h[j] = (__bf16)(float)a[j];
    h[j + 4] = (__bf16)(float)b[j];
  }
  return h;
}

template <int MODE>  // 1: W preconv; 2: no workspace
__global__ void __launch_bounds__(256, 2) gemm_fb_kernel(
    const float* __restrict__ X, const __bf16* __restrict__ Wb,
    const int* __restrict__ Wq, const float* __restrict__ scale,
    const float* __restrict__ bias, float* __restrict__ out) {
  __shared__ __align__(16) __bf16 As[FBM * FBK];
  __shared__ __align__(16) __bf16 Bs[FBN * FBK];

  const int tid = threadIdx.x;
  const int lane = tid & 63;
  const int wv = tid >> 6;

  const int lid = blockIdx.x;
  const int swz = (lid & 7) * ((FMT * FNT) >> 3) + (lid >> 3);
  const int tm = swz / FNT;
  const int tn = swz - tm * FNT;
  const int m0 = tm * FBM;
  const int n0 = tn * FBN;

  const int e0 = wv * 512 + lane * 8;
  const int e1 = e0 + 2048;
  const int r0 = e0 >> 5, c0 = e0 & 31;
  const int r1 = e1 >> 5, c1 = e1 & 31;

  f32x4 acc[4][4];
#pragma unroll
  for (int m = 0; m < 4; ++m)
#pragma unroll
    for (int n = 0; n < 4; ++n) acc[m][n] = (f32x4){0.f, 0.f, 0.f, 0.f};

  const int wm = (wv >> 1) * 64;
  const int wn = (wv & 1) * 64;
  const int fr = lane & 15;
  const int kc = (lane >> 4) * 8;

  const float* srcAf0 = X + (size_t)(m0 + r0) * K_DIM + c0;
  const float* srcAf1 = X + (size_t)(m0 + r1) * K_DIM + c1;
  const __bf16* srcBb0 = Wb + (size_t)(n0 + r0) * K_DIM + c0;
  const __bf16* srcBb1 = Wb + (size_t)(n0 + r1) * K_DIM + c1;
  const int* srcQ0 = Wq + (size_t)(n0 + r0) * K_DIM + c0;
  const int* srcQ1 = Wq + (size_t)(n0 + r1) * K_DIM + c1;

  for (int k0 = 0; k0 < K_DIM; k0 += FBK) {
    f32x4 a0 = *(const f32x4*)(srcAf0 + k0);
    f32x4 a1 = *(const f32x4*)(srcAf0 + k0 + 4);
    f32x4 a2 = *(const f32x4*)(srcAf1 + k0);
    f32x4 a3 = *(const f32x4*)(srcAf1 + k0 + 4);
    if constexpr (MODE == 1) {
      gload_lds16(srcBb0 + k0, &Bs[e0]);
      gload_lds16(srcBb1 + k0, &Bs[e1]);
    } else {
      i32x4 q0 = *(const i32x4*)(srcQ0 + k0);
      i32x4 q1 = *(const i32x4*)(srcQ0 + k0 + 4);
      i32x4 q2 = *(const i32x4*)(srcQ1 + k0);
      i32x4 q3 = *(const i32x4*)(srcQ1 + k0 + 4);
      *(bf16x8*)&Bs[e0] = cvt8i(q0, q1);
      *(bf16x8*)&Bs[e1] = cvt8i(q2, q3);
    }
    *(bf16x8*)&As[e0] = cvt8f(a0, a1);
    *(bf16x8*)&As[e1] = cvt8f(a2, a3);
    __syncthreads();

    bf16x8 a[4], b[4];
#pragma unroll
    for (int m = 0; m < 4; ++m)
      a[m] = *(const bf16x8*)&As[(wm + m * 16 + fr) * FBK + kc];
#pragma unroll
    for (int n = 0; n < 4; ++n)
      b[n] = *(const bf16x8*)&Bs[(wn + n * 16 + fr) * FBK + kc];
#pragma unroll
    for (int m = 0; m < 4; ++m)
#pragma unroll
      for (int n = 0; n < 4; ++n)
        acc[m][n] = __builtin_amdgcn_mfma_f32_16x16x32_bf16(a[m], b[n],
                                                            acc[m][n], 0, 0, 0);
    __syncthreads();
  }

  const int cc = lane & 15;
  const int rr = (lane >> 4) * 4;
#pragma unroll
  for (int n = 0; n < 4; ++n) {
    const int col = n0 + wn + n * 16 + cc;
    const float sc = scale[col];
    const float bi = bias[col];
#pragma unroll
    for (int m = 0; m < 4; ++m) {
      const int rowb = m0 + wm + m * 16 + rr;
#pragma unroll
      for (int r = 0; r < 4; ++r) {
        out[(size_t)(rowb + r) * N_DIM + col] = acc[m][n][r] * sc + bi;
      }
    }
  }
}

// ---------------- launch ----------------

extern "C" void kernel_launch(void* const* d_in, const int* in_sizes, int n_in,
                              void* d_out, int out_size, void* d_ws, size_t ws_size,
                              hipStream_t stream) {
  const float* X = (const float*)d_in[0];
  const int* Wq = (const int*)d_in[1];
  const float* scale = (const float*)d_in[2];
  const float* bias = (const float*)d_in[3];
  float* out = (float*)d_out;

  const size_t wbytes = (size_t)N_DIM * K_DIM * sizeof(__bf16);  // 90,177,536
  const size_t xbytes = (size_t)M_DIM * K_DIM * sizeof(__bf16);  // 67,108,864
  const int n8w = (N_DIM * K_DIM) / 8;
  const int n8x = (M_DIM * K_DIM) / 8;

  if (ws_size >= wbytes + xbytes) {
    __bf16* Wb = (__bf16*)d_ws;
    __bf16* Xb = (__bf16*)((char*)d_ws + wbytes);
    wconv_kernel<<<dim3((n8w + 255) / 256), dim3(256), 0, stream>>>(Wq, Wb, n8w);
    xconv_kernel<<<dim3((n8x + 255) / 256), dim3(256), 0, stream>>>(X, Xb, n8x);
    gemm256_kernel<<<dim3(NBLK), dim3(512), 0, stream>>>(Xb, Wb, scale, bias, out);
  } else if (ws_size >= wbytes) {
    __bf16* Wb = (__bf16*)d_ws;
    wconv_kernel<<<dim3((n8w + 255) / 256), dim3(256), 0, stream>>>(Wq, Wb, n8w);
    gemm_fb_kernel<1><<<dim3(FMT * FNT), dim3(256), 0, stream>>>(
        X, Wb, Wq, scale, bias, out);
  } else {
    gemm_fb_kernel<2><<<dim3(FMT * FNT), dim3(256), 0, stream>>>(
        X, nullptr, Wq, scale, bias, out);
  }
}